// Round 11
// baseline (1977.743 us; speedup 1.0000x reference)
//
#include <hip/hip_runtime.h>
#include <hip/hip_bf16.h>

// SRNN: x_{t+1} = x + DT*(-x + J@rates + inp), rates = 0.5*(1+tanh(x)),
// out[p,t] = (w_out @ rates_t)[p] / N.
//
// v11: PERSISTENT dense-MFMA kernel, custom lightweight grid barrier.
//  - GEMM core = v10 (proven bit-exact): BM=64 BN=32 BK=128, 16 phases,
//    8 waves, 4-buf LDS, counted vmcnt(6/3/0), XOR-16 chunk swizzle,
//    XCD-contiguous m-panels.
//  - barrier: plain rates stores -> fence(release,"agent") by tid0 (wbl2 of
//    ~128KB dirty/XCD) -> device-scope atomicAdd arrive -> spin w/ s_sleep.
//    NO acquire/L2-inv on readers: B staged via global_load_lds aux=16
//    (SC1=device scope, bypasses stale L1/L2, reads LLC). J stays L2-hot
//    across all 200 steps; x/patterns/w_out live in registers all run.
//  - cg::grid.sync measured 125us/step (r4) -- this replaces its protocol.
// [history: sparse plateau 2114-2360 (v2/v7/v8); v9 dense 4-wave 2119;
//  v10 dense 8-wave 1972 (~2.4us/step launch tax + per-step state reloads).]

#define NN 2048
#define PP 256
#define DT_C 0.1f
#define ON_TIME_C 10

typedef __attribute__((ext_vector_type(8))) short bf16x8;
typedef __attribute__((ext_vector_type(4))) float f32x4;

__device__ __forceinline__ unsigned short bf16rne(float f) {
    unsigned b = __float_as_uint(f);
    return (unsigned short)((b + 0x7FFFu + ((b >> 16) & 1u)) >> 16);
}
__device__ __forceinline__ int kperm(int s) {
    return ((s & 15) >> 2) * 8 + (s & 3) + ((s >> 4) << 2);
}

__global__ void convert_J_kernel(const float* __restrict__ J,
                                 unsigned short* __restrict__ Jp) {
    int i = blockIdx.x * blockDim.x + threadIdx.x;
    int row = i >> 11, k = i & 2047;
    Jp[((size_t)row << 11) + (k & ~31) + kperm(k & 31)] = bf16rne(J[i]);
}

__global__ void init_kernel(float* __restrict__ x,
                            unsigned short* __restrict__ rT,
                            float* __restrict__ out, int nout,
                            unsigned* __restrict__ cnt) {
    int i = blockIdx.x * blockDim.x + threadIdx.x;
    x[i] = 0.0f;
    rT[i] = 0x3F00;
    if (i < nout) out[i] = 0.0f;
    if (i == 0) *cnt = 0u;
}

#define AS1 __attribute__((address_space(1)))
#define AS3 __attribute__((address_space(3)))
#define GLOADA(g, l) \
    __builtin_amdgcn_global_load_lds((const AS1 void*)(g), (AS3 void*)(l), 16, 0, 0)
#define GLOADB(g, l) \
    __builtin_amdgcn_global_load_lds((const AS1 void*)(g), (AS3 void*)(l), 16, 0, 16)

// ================= persistent all-steps kernel =================
__global__ __launch_bounds__(512, 1) void srnn_persist(
    const unsigned short* __restrict__ Jp,
    unsigned short* __restrict__ r0, unsigned short* __restrict__ r1,
    const float* __restrict__ patterns, const float* __restrict__ w_out,
    float* __restrict__ out, unsigned* __restrict__ cnt, int T) {

    __shared__ char smem[98304];              // 4 bufs x (A 16KB + B 8KB)

    const int tid  = threadIdx.x;
    const int w    = tid >> 6;
    const int lane = tid & 63;
    const int wm   = w >> 1, wn = w & 1;

    const int bid   = (blockIdx.x & 7) * 32 + (blockIdx.x >> 3);
    const int mbase = (bid >> 3) * 64;
    const int nbase = (bid & 7) * 32;

    const int rA0 = 8 * w + (lane >> 4);
    const int rA1 = rA0 + 4;
    const int rB  = 4 * w + (lane >> 4);
    const char* gA0 = (const char*)Jp + (((size_t)(mbase + rA0)) << 12)
                      + (((lane & 15) ^ (rA0 & 15)) << 4);
    const char* gA1 = (const char*)Jp + (((size_t)(mbase + rA1)) << 12)
                      + (((lane & 15) ^ (rA1 & 15)) << 4);
    const size_t gBoff = (((size_t)(nbase + rB)) << 12)
                      + (((lane & 15) ^ (rB & 15)) << 4);
    const int ldsA0 = (8 * w) * 256, ldsA1 = (8 * w + 4) * 256;
    const int ldsB  = 16384 + 4 * w * 256;

    const int mr = wm * 16 + (lane & 15);
    const int nr = wn * 16 + (lane & 15);
    const int nloc = wn * 16 + (lane & 15);
    const int n    = nbase + nloc;

    // ---- persistent per-thread state: x, pattern, readout scale ----
    float xv[4], pat[4], wsc[4];
    #pragma unroll
    for (int rg = 0; rg < 4; ++rg) {
        int m = mbase + wm * 16 + (lane >> 4) * 4 + rg;
        size_t o = ((size_t)m << 8) + n;
        xv[rg]  = 0.0f;
        pat[rg] = patterns[o];
        wsc[rg] = (w_out[m] != 0.0f) ? (1.0f / (float)NN) : 0.0f;
    }

    for (int t = 0; t < T; ++t) {
        const char* rbas = (t & 1) ? (const char*)r1 : (const char*)r0;
        char*       robs = (t & 1) ? (char*)r0 : (char*)r1;
        const char* gB   = rbas + gBoff;

        // prologue: stage phases 0,1
        GLOADA(gA0,       smem + 0 * 24576 + ldsA0);
        GLOADA(gA1,       smem + 0 * 24576 + ldsA1);
        GLOADB(gB,        smem + 0 * 24576 + ldsB);
        GLOADA(gA0 + 256, smem + 1 * 24576 + ldsA0);
        GLOADA(gA1 + 256, smem + 1 * 24576 + ldsA1);
        GLOADB(gB  + 256, smem + 1 * 24576 + ldsB);

        f32x4 acc = {0.f, 0.f, 0.f, 0.f};

        #pragma unroll
        for (int ph = 0; ph < 16; ++ph) {
            if (ph < 14) {
                const int bo = ((ph + 2) & 3) * 24576;
                GLOADA(gA0 + (ph + 2) * 256, smem + bo + ldsA0);
                GLOADA(gA1 + (ph + 2) * 256, smem + bo + ldsA1);
                GLOADB(gB  + (ph + 2) * 256, smem + bo + ldsB);
            }
            if (ph < 14)       asm volatile("s_waitcnt vmcnt(6)" ::: "memory");
            else if (ph == 14) asm volatile("s_waitcnt vmcnt(3)" ::: "memory");
            else               asm volatile("s_waitcnt vmcnt(0)" ::: "memory");
            __builtin_amdgcn_s_barrier();
            __builtin_amdgcn_sched_barrier(0);

            const int bb = (ph & 3) * 24576;
            bf16x8 a[4], b[4];
            #pragma unroll
            for (int g = 0; g < 4; ++g) {
                int c = g * 4 + (lane >> 4);
                a[g] = *(const bf16x8*)(smem + bb + mr * 256 + ((c ^ (mr & 15)) << 4));
                b[g] = *(const bf16x8*)(smem + bb + 16384 + nr * 256 + ((c ^ (nr & 15)) << 4));
            }
            #pragma unroll
            for (int g = 0; g < 4; ++g)
                acc = __builtin_amdgcn_mfma_f32_16x16x32_bf16(a[g], b[g], acc, 0, 0, 0);
        }

        __syncthreads();                      // buffers dead; reuse as s_out

        // ---- epilogue: x (registers), tanh, readout, LDS transpose ----
        #pragma unroll
        for (int rg = 0; rg < 4; ++rg) {
            float xo = xv[rg];
            float inp = (t < ON_TIME_C) ? pat[rg] : 0.0f;
            float xn = xo + DT_C * (acc[rg] + inp - xo);
            xv[rg] = xn;
            float r = 0.5f * (1.0f + tanhf(xn));
            if (wsc[rg] != 0.0f)
                atomicAdd(&out[(size_t)n * T + t], r * wsc[rg]);
            int mloc = wm * 16 + (lane >> 4) * 4 + rg;
            int pos  = (mloc & ~31) + kperm(mloc & 31);
            int byte = nloc * 128 + (((pos >> 3) ^ (nloc & 7)) << 4) + (pos & 7) * 2;
            *(unsigned short*)(smem + byte) = bf16rne(r);
        }
        __syncthreads();
        if (tid < 256) {                      // write [32 n][64 m] slab
            int nl = tid >> 3, p = tid & 7;
            uint4 v = *(const uint4*)(smem + nl * 128 + ((p ^ (nl & 7)) << 4));
            *(uint4*)(robs + (((size_t)(nbase + nl)) << 12) + mbase * 2 + p * 16) = v;
        }
        __syncthreads();                      // each wave drains vmcnt pre-barrier

        // ---- custom grid barrier (monotone counter) ----
        if (tid == 0) {
            __builtin_amdgcn_fence(__ATOMIC_RELEASE, "agent");   // wbl2 dirty lines
            __hip_atomic_fetch_add(cnt, 1u, __ATOMIC_RELAXED,
                                   __HIP_MEMORY_SCOPE_AGENT);
            unsigned tgt = 256u * (unsigned)(t + 1);
            while (__hip_atomic_load(cnt, __ATOMIC_RELAXED,
                                     __HIP_MEMORY_SCOPE_AGENT) < tgt)
                __builtin_amdgcn_s_sleep(4);
        }
        __syncthreads();
    }
}

// ================= fallback per-step kernel (v10, proven 1972us) =========
__global__ __launch_bounds__(512, 1) void gemm_step_kernel(
    const unsigned short* __restrict__ Jp,
    const unsigned short* __restrict__ rin, unsigned short* __restrict__ rout,
    float* __restrict__ x, const float* __restrict__ patterns,
    const float* __restrict__ w_out, float* __restrict__ out,
    int t, int T, int with_input) {

    __shared__ char smem[98304];
    const int tid  = threadIdx.x;
    const int w    = tid >> 6;
    const int lane = tid & 63;
    const int wm   = w >> 1, wn = w & 1;
    const int bid   = (blockIdx.x & 7) * 32 + (blockIdx.x >> 3);
    const int mbase = (bid >> 3) * 64;
    const int nbase = (bid & 7) * 32;

    const int rA0 = 8 * w + (lane >> 4);
    const int rA1 = rA0 + 4;
    const int rB  = 4 * w + (lane >> 4);
    const char* gA0 = (const char*)Jp  + (((size_t)(mbase + rA0)) << 12)
                      + (((lane & 15) ^ (rA0 & 15)) << 4);
    const char* gA1 = (const char*)Jp  + (((size_t)(mbase + rA1)) << 12)
                      + (((lane & 15) ^ (rA1 & 15)) << 4);
    const char* gB  = (const char*)rin + (((size_t)(nbase + rB )) << 12)
                      + (((lane & 15) ^ (rB  & 15)) << 4);
    const int ldsA0 = (8 * w) * 256, ldsA1 = (8 * w + 4) * 256;
    const int ldsB  = 16384 + 4 * w * 256;
    const int mr = wm * 16 + (lane & 15);
    const int nr = wn * 16 + (lane & 15);

    float xv[4], pat[4], wsc[4];
    #pragma unroll
    for (int rg = 0; rg < 4; ++rg) {
        int m = mbase + wm * 16 + (lane >> 4) * 4 + rg;
        int n = nbase + wn * 16 + (lane & 15);
        size_t o = ((size_t)m << 8) + n;
        xv[rg]  = x[o];
        pat[rg] = with_input ? patterns[o] : 0.0f;
        wsc[rg] = (w_out[m] != 0.0f) ? (1.0f / (float)NN) : 0.0f;
    }

    f32x4 acc = {0.f, 0.f, 0.f, 0.f};
    GLOADA(gA0,       smem + 0 * 24576 + ldsA0);
    GLOADA(gA1,       smem + 0 * 24576 + ldsA1);
    GLOADA(gB,        smem + 0 * 24576 + ldsB);
    GLOADA(gA0 + 256, smem + 1 * 24576 + ldsA0);
    GLOADA(gA1 + 256, smem + 1 * 24576 + ldsA1);
    GLOADA(gB  + 256, smem + 1 * 24576 + ldsB);

    #pragma unroll
    for (int ph = 0; ph < 16; ++ph) {
        if (ph < 14) {
            const int bo = ((ph + 2) & 3) * 24576;
            GLOADA(gA0 + (ph + 2) * 256, smem + bo + ldsA0);
            GLOADA(gA1 + (ph + 2) * 256, smem + bo + ldsA1);
            GLOADA(gB  + (ph + 2) * 256, smem + bo + ldsB);
        }
        if (ph < 14)       asm volatile("s_waitcnt vmcnt(6)" ::: "memory");
        else if (ph == 14) asm volatile("s_waitcnt vmcnt(3)" ::: "memory");
        else               asm volatile("s_waitcnt vmcnt(0)" ::: "memory");
        __builtin_amdgcn_s_barrier();
        __builtin_amdgcn_sched_barrier(0);

        const int bb = (ph & 3) * 24576;
        bf16x8 a[4], b[4];
        #pragma unroll
        for (int g = 0; g < 4; ++g) {
            int c = g * 4 + (lane >> 4);
            a[g] = *(const bf16x8*)(smem + bb + mr * 256 + ((c ^ (mr & 15)) << 4));
            b[g] = *(const bf16x8*)(smem + bb + 16384 + nr * 256 + ((c ^ (nr & 15)) << 4));
        }
        #pragma unroll
        for (int g = 0; g < 4; ++g)
            acc = __builtin_amdgcn_mfma_f32_16x16x32_bf16(a[g], b[g], acc, 0, 0, 0);
    }

    __syncthreads();
    #pragma unroll
    for (int rg = 0; rg < 4; ++rg) {
        float xo = xv[rg];
        float xn = xo + DT_C * (acc[rg] + pat[rg] - xo);
        int mloc = wm * 16 + (lane >> 4) * 4 + rg;
        int nloc = wn * 16 + (lane & 15);
        int m = mbase + mloc, n = nbase + nloc;
        x[((size_t)m << 8) + n] = xn;
        float r = 0.5f * (1.0f + tanhf(xn));
        if (wsc[rg] != 0.0f)
            atomicAdd(&out[(size_t)n * T + t], r * wsc[rg]);
        int pos  = (mloc & ~31) + kperm(mloc & 31);
        int byte = nloc * 128 + (((pos >> 3) ^ (nloc & 7)) << 4) + (pos & 7) * 2;
        *(unsigned short*)(smem + byte) = bf16rne(r);
    }
    __syncthreads();
    if (tid < 256) {
        int nl = tid >> 3, p = tid & 7;
        uint4 v = *(const uint4*)(smem + nl * 128 + ((p ^ (nl & 7)) << 4));
        *(uint4*)((char*)rout + (((size_t)(nbase + nl)) << 12) + mbase * 2 + p * 16) = v;
    }
}

extern "C" void kernel_launch(void* const* d_in, const int* in_sizes, int n_in,
                              void* d_out, int out_size, void* d_ws, size_t ws_size,
                              hipStream_t stream) {
    const float* patterns = (const float*)d_in[0];   // [N, P]
    const float* J        = (const float*)d_in[1];   // [N, N]
    const float* w_out    = (const float*)d_in[2];   // [N]
    float* out            = (float*)d_out;           // [P, T]

    int T = out_size / PP;                           // 200

    size_t off = 0;
    auto alloc = [&](size_t bytes) {
        void* p = (char*)d_ws + off;
        off += (bytes + 255) & ~(size_t)255;
        return p;
    };
    unsigned short* Jp  = (unsigned short*)alloc((size_t)NN * NN * 2);  // 8MB
    unsigned short* r0  = (unsigned short*)alloc((size_t)PP * NN * 2);  // 1MB
    unsigned short* r1  = (unsigned short*)alloc((size_t)PP * NN * 2);  // 1MB
    float*          x   = (float*)         alloc((size_t)NN * PP * 4);  // 2MB
    unsigned*       cnt = (unsigned*)      alloc(256);
    (void)ws_size; (void)n_in; (void)in_sizes;

    convert_J_kernel<<<(NN * NN) / 256, 256, 0, stream>>>(J, Jp);
    init_kernel<<<(NN * PP) / 256, 256, 0, stream>>>(x, r0, out, PP * T, cnt);

    // persistent path: cooperative launch (co-residency guarantee), custom sync
    int mb = 0;
    if (hipOccupancyMaxActiveBlocksPerMultiprocessor(
            &mb, (const void*)srnn_persist, 512, 0) == hipSuccess && mb >= 1) {
        void* args[] = {(void*)&Jp, (void*)&r0, (void*)&r1, (void*)&patterns,
                        (void*)&w_out, (void*)&out, (void*)&cnt, (void*)&T};
        if (hipLaunchCooperativeKernel((const void*)srnn_persist,
                                       dim3(256), dim3(512), args, 0,
                                       stream) == hipSuccess)
            return;
    }

    // fallback: v10 per-step loop (proven 1972us)
    for (int t = 0; t < T; ++t) {
        const unsigned short* rin = (t & 1) ? r1 : r0;
        unsigned short*      rout = (t & 1) ? r0 : r1;
        gemm_step_kernel<<<256, 512, 0, stream>>>(Jp, rin, rout, x, patterns,
                                                  w_out, out, t, T,
                                                  (t < ON_TIME_C) ? 1 : 0);
    }
}

// Round 12
// 1931.534 us; speedup vs baseline: 1.0239x; 1.0239x over previous
//
#include <hip/hip_runtime.h>
#include <hip/hip_bf16.h>

// SRNN: x_{t+1} = x + DT*(-x + J@rates + inp), rates = 0.5*(1+tanh(x)),
// out[p,t] = (w_out @ rates_t)[p] / N.
//
// v12 = v10 step structure with the MFMA shape switched 16x16x32 ->
// 32x32x16, which halves LDS bytes/MAC (0.25 -> 0.125 B/MAC):
//  - v10 was LDS-read-bound: 1x1 acc/wave => 2 ds_read_b128 per MFMA =
//    1MB/CU/step ~ 5.1us. Now: wave = (subtile s in {0,1} of 32x32,
//    K-quarter kq in {0..3}); per BK=128 phase a wave does slices
//    {2kq, 2kq+1}: 2 MFMA(32x32x16) + 4 ds_read -> 512KB/CU/step.
//  - end of K-loop: 4-way kq reduction of f32x16 partials through LDS,
//    then epilogue (x update, tanh, atomic readout, LDS transpose of
//    rates_T) -- same machinery as v10.
//  - staging, XOR-16 chunk swizzle, 4-buf LDS, counted vmcnt(6/3/0),
//    16 phases, XCD-contiguous m-panels: byte-identical to v10.
//  - k-permutation now per-16 group (kperm16: lane-half h holds source
//    ks {4h+j, 8+4h+j}), the 32x32x16 analog of v9/v10's verified kperm32.
//  - C-layout 32x32: col=lane&31, row=(reg&3)+8*(reg>>2)+4*(lane>>5).
// [history: sparse plateau 2114-2360; coop grid.sync 25ms; custom-barrier
//  persistent 22.5us/step (256x wbl2 + SC1 loads); v9 2119; v10 1972.]

#define NN 2048
#define PP 256
#define DT_C 0.1f
#define ON_TIME_C 10

typedef __attribute__((ext_vector_type(8)))  short bf16x8;
typedef __attribute__((ext_vector_type(16))) float f32x16;

__device__ __forceinline__ unsigned short bf16rne(float f) {
    unsigned b = __float_as_uint(f);
    return (unsigned short)((b + 0x7FFFu + ((b >> 16) & 1u)) >> 16);
}
// 32x32x16 fragment permutation within a 16-k group: source k s -> position.
// lane-half h holds {4h+0..3, 8+4h+0..3} in order.
__device__ __forceinline__ int kperm16(int s) {
    return (s & 3) + (((s >> 2) & 1) << 3) + ((s >> 3) << 2);
}

// ---- J f32 [N][N] -> bf16 [N][N], k-permuted per 16-group ----
__global__ void convert_J_kernel(const float* __restrict__ J,
                                 unsigned short* __restrict__ Jp) {
    int i = blockIdx.x * blockDim.x + threadIdx.x;   // grid covers NN*NN
    int row = i >> 11, k = i & 2047;
    Jp[((size_t)row << 11) + (k & ~15) + kperm16(k & 15)] = bf16rne(J[i]);
}

// ---- x = 0, rates_T = bf16(0.5) (perm-invariant), out = 0 ----
__global__ void init_kernel(float* __restrict__ x,
                            unsigned short* __restrict__ rT,
                            float* __restrict__ out, int nout) {
    int i = blockIdx.x * blockDim.x + threadIdx.x;   // grid covers NN*PP
    x[i] = 0.0f;
    rT[i] = 0x3F00;
    if (i < nout) out[i] = 0.0f;
}

#define AS1 __attribute__((address_space(1)))
#define AS3 __attribute__((address_space(3)))
#define GLOAD16(g, l) \
    __builtin_amdgcn_global_load_lds((const AS1 void*)(g), (AS3 void*)(l), 16, 0, 0)

// ---- One time step. grid 256 (1/CU), 512 thr (8 waves). BM=64 BN=32. ----
__global__ __launch_bounds__(512, 1) void gemm_step_kernel(
    const unsigned short* __restrict__ Jp,    // [N][N] bf16 kperm16'd
    const unsigned short* __restrict__ rin,   // rates_T [P][N] bf16 kperm16'd
    unsigned short* __restrict__ rout,        // rates_T [P][N]
    float* __restrict__ x, const float* __restrict__ patterns,
    const float* __restrict__ w_out, float* __restrict__ out,
    int t, int T, int with_input) {

    __shared__ char smem[98304];              // 4 bufs x (A 16KB + B 8KB)

    const int tid  = threadIdx.x;
    const int w    = tid >> 6;                // wave 0..7
    const int lane = tid & 63;
    const int s    = w >> 2;                  // subtile (32 m-rows)
    const int kq   = w & 3;                   // K-quarter role
    const int h    = lane >> 5;               // k-half within fragment

    // XCD-contiguous swizzle: XCD owns 4 contiguous m-panels.
    const int bid   = (blockIdx.x & 7) * 32 + (blockIdx.x >> 3);
    const int mbase = (bid >> 3) * 64;
    const int nbase = (bid & 7) * 32;

    // ---- staging (identical to v10): wave stages A rows 8w..+8, B rows 4w..+4 ----
    const int rA0 = 8 * w + (lane >> 4);
    const int rA1 = rA0 + 4;
    const int rB  = 4 * w + (lane >> 4);
    const char* gA0 = (const char*)Jp  + (((size_t)(mbase + rA0)) << 12)
                      + (((lane & 15) ^ (rA0 & 15)) << 4);
    const char* gA1 = (const char*)Jp  + (((size_t)(mbase + rA1)) << 12)
                      + (((lane & 15) ^ (rA1 & 15)) << 4);
    const char* gB  = (const char*)rin + (((size_t)(nbase + rB )) << 12)
                      + (((lane & 15) ^ (rB  & 15)) << 4);
    const int ldsA0 = (8 * w) * 256, ldsA1 = (8 * w + 4) * 256;
    const int ldsB  = 16384 + 4 * w * 256;

    // ---- fragment read rows ----
    const int rA = 32 * s + (lane & 31);      // A row (local, 0..63)
    const int rBn = lane & 31;                // B row (local n, 0..31)

    f32x16 acc = {};

    // prologue: stage phases 0,1
    GLOAD16(gA0,       smem + 0 * 24576 + ldsA0);
    GLOAD16(gA1,       smem + 0 * 24576 + ldsA1);
    GLOAD16(gB,        smem + 0 * 24576 + ldsB);
    GLOAD16(gA0 + 256, smem + 1 * 24576 + ldsA0);
    GLOAD16(gA1 + 256, smem + 1 * 24576 + ldsA1);
    GLOAD16(gB  + 256, smem + 1 * 24576 + ldsB);

    // ---- K-loop: 16 phases of BK=128; wave computes slices 2kq, 2kq+1 ----
    #pragma unroll
    for (int ph = 0; ph < 16; ++ph) {
        if (ph < 14) {
            const int bo = ((ph + 2) & 3) * 24576;
            GLOAD16(gA0 + (ph + 2) * 256, smem + bo + ldsA0);
            GLOAD16(gA1 + (ph + 2) * 256, smem + bo + ldsA1);
            GLOAD16(gB  + (ph + 2) * 256, smem + bo + ldsB);
        }
        if (ph < 14)       asm volatile("s_waitcnt vmcnt(6)" ::: "memory");
        else if (ph == 14) asm volatile("s_waitcnt vmcnt(3)" ::: "memory");
        else               asm volatile("s_waitcnt vmcnt(0)" ::: "memory");
        __builtin_amdgcn_s_barrier();
        __builtin_amdgcn_sched_barrier(0);

        const int bb = (ph & 3) * 24576;
        #pragma unroll
        for (int sl = 0; sl < 2; ++sl) {
            const int c = kq * 4 + sl * 2 + h;    // 16B chunk in 256B row
            bf16x8 a = *(const bf16x8*)(smem + bb + rA * 256
                                        + ((c ^ (rA & 15)) << 4));
            bf16x8 b = *(const bf16x8*)(smem + bb + 16384 + rBn * 256
                                        + ((c ^ (rBn & 15)) << 4));
            acc = __builtin_amdgcn_mfma_f32_32x32x16_bf16(a, b, acc, 0, 0, 0);
        }
    }

    __syncthreads();                          // all reads done; reuse smem

    // ---- write kq-partials: plane (s*4+kq), [32 row][32 col] f32 ----
    {
        float* pf = (float*)smem;
        const int plane = (s * 4 + kq) * 1024;
        #pragma unroll
        for (int reg = 0; reg < 16; ++reg) {
            int row = (reg & 3) + 8 * (reg >> 2) + 4 * h;
            pf[plane + row * 32 + (lane & 31)] = acc[reg];
        }
    }
    __syncthreads();

    // ---- reduce 4 kq-planes + epilogue. thread -> (s2, rr, 4 cols) ----
    {
        const int s2 = tid >> 8, rr = (tid >> 3) & 31, c4 = (tid & 7) * 4;
        const float4* pf4 = (const float4*)smem;
        int base = ((s2 * 4) * 1024 + rr * 32 + c4) >> 2;   // float4 index
        float4 v0 = pf4[base], v1 = pf4[base + 256];
        float4 v2 = pf4[base + 512], v3 = pf4[base + 768];
        float sum[4] = {v0.x + v1.x + v2.x + v3.x, v0.y + v1.y + v2.y + v3.y,
                        v0.z + v1.z + v2.z + v3.z, v0.w + v1.w + v2.w + v3.w};

        const int mloc = s2 * 32 + rr;
        const int m = mbase + mloc;
        const int n0 = nbase + c4;
        size_t xo = ((size_t)m << 8) + n0;
        float4 xv = *(const float4*)(x + xo);
        float4 pv = make_float4(0.f, 0.f, 0.f, 0.f);
        if (with_input) pv = *(const float4*)(patterns + xo);
        float wsc = (w_out[m] != 0.0f) ? (1.0f / (float)NN) : 0.0f;

        float xn[4] = {xv.x + DT_C * (sum[0] + pv.x - xv.x),
                       xv.y + DT_C * (sum[1] + pv.y - xv.y),
                       xv.z + DT_C * (sum[2] + pv.z - xv.z),
                       xv.w + DT_C * (sum[3] + pv.w - xv.w)};
        *(float4*)(x + xo) = make_float4(xn[0], xn[1], xn[2], xn[3]);

        const int pos = (mloc & ~15) + kperm16(mloc & 15);
        #pragma unroll
        for (int j = 0; j < 4; ++j) {
            float r = 0.5f * (1.0f + tanhf(xn[j]));
            if (wsc != 0.0f)
                atomicAdd(&out[(size_t)(n0 + j) * T + t], r * wsc);
            int nloc = c4 + j;
            int byte = 32768 + nloc * 128
                     + (((pos >> 3) ^ (nloc & 7)) << 4) + (pos & 7) * 2;
            *(unsigned short*)(smem + byte) = bf16rne(r);
        }
    }
    __syncthreads();
    if (tid < 256) {   // linear write-out of the block's [32 n][64 m] slab
        int nl = tid >> 3, p = tid & 7;
        uint4 v = *(const uint4*)(smem + 32768 + nl * 128 + ((p ^ (nl & 7)) << 4));
        *(uint4*)((char*)rout + (((size_t)(nbase + nl)) << 12) + mbase * 2 + p * 16) = v;
    }
}

extern "C" void kernel_launch(void* const* d_in, const int* in_sizes, int n_in,
                              void* d_out, int out_size, void* d_ws, size_t ws_size,
                              hipStream_t stream) {
    const float* patterns = (const float*)d_in[0];   // [N, P]
    const float* J        = (const float*)d_in[1];   // [N, N]
    const float* w_out    = (const float*)d_in[2];   // [N]
    float* out            = (float*)d_out;           // [P, T]

    int T = out_size / PP;                           // 200

    size_t off = 0;
    auto alloc = [&](size_t bytes) {
        void* p = (char*)d_ws + off;
        off += (bytes + 255) & ~(size_t)255;
        return p;
    };
    unsigned short* Jp = (unsigned short*)alloc((size_t)NN * NN * 2);  // 8MB
    unsigned short* r0 = (unsigned short*)alloc((size_t)PP * NN * 2);  // 1MB
    unsigned short* r1 = (unsigned short*)alloc((size_t)PP * NN * 2);  // 1MB
    float*          x  = (float*)         alloc((size_t)NN * PP * 4);  // 2MB
    (void)ws_size; (void)n_in; (void)in_sizes;

    convert_J_kernel<<<(NN * NN) / 256, 256, 0, stream>>>(J, Jp);
    init_kernel<<<(NN * PP) / 256, 256, 0, stream>>>(x, r0, out, PP * T);

    for (int t = 0; t < T; ++t) {
        const unsigned short* rin = (t & 1) ? r1 : r0;
        unsigned short*      rout = (t & 1) ? r0 : r1;
        gemm_step_kernel<<<256, 512, 0, stream>>>(Jp, rin, rout, x, patterns,
                                                  w_out, out, t, T,
                                                  (t < ON_TIME_C) ? 1 : 0);
    }
}